// Round 1
// baseline (757.253 us; speedup 1.0000x reference)
//
#include <hip/hip_runtime.h>
#include <math.h>

#define LSEQ 2048
#define DI 512
#define DS 64
#define DTRANK 8
#define CIN 128
#define NB 4

__device__ __forceinline__ float silu_f(float v) { return v / (1.f + __expf(-v)); }

// ---------------- GEMM1: in_proj ----------------
// per b: O[j(1024), l(2048)] = Wi[1024,128] @ x_b[128,2048]
// j<512 -> xi_t[b][j][l], j>=512 -> z_t[b][j-512][l]
__global__ __launch_bounds__(256) void gemm_inproj(
    const float* __restrict__ x, const float* __restrict__ Wi,
    float* __restrict__ xi_t, float* __restrict__ z_t) {
  __shared__ float As[16][68];  // [k][j]
  __shared__ float Bs[16][68];  // [k][l]
  int tid = threadIdx.x;
  int tx = tid & 15, ty = tid >> 4;
  int l0 = blockIdx.x * 64, j0 = blockIdx.y * 64, b = blockIdx.z;
  const float* xb = x + (size_t)b * CIN * LSEQ;
  float acc[4][4] = {};
  for (int k0 = 0; k0 < CIN; k0 += 16) {
    {
      int kk = tid & 15, jj = tid >> 4;
#pragma unroll
      for (int i = 0; i < 4; ++i)
        As[kk][jj + 16 * i] = Wi[(size_t)(j0 + jj + 16 * i) * CIN + k0 + kk];
    }
    {
      int ll = tid & 63, kk = tid >> 6;
#pragma unroll
      for (int i = 0; i < 4; ++i)
        Bs[kk + 4 * i][ll] = xb[(size_t)(k0 + kk + 4 * i) * LSEQ + l0 + ll];
    }
    __syncthreads();
#pragma unroll
    for (int k = 0; k < 16; ++k) {
      float4 a = *(const float4*)&As[k][ty * 4];
      float4 bv = *(const float4*)&Bs[k][tx * 4];
      float av[4] = {a.x, a.y, a.z, a.w};
      float bw[4] = {bv.x, bv.y, bv.z, bv.w};
#pragma unroll
      for (int i = 0; i < 4; ++i)
#pragma unroll
        for (int j = 0; j < 4; ++j) acc[i][j] = fmaf(av[i], bw[j], acc[i][j]);
    }
    __syncthreads();
  }
#pragma unroll
  for (int i = 0; i < 4; ++i) {
    int j = j0 + ty * 4 + i;
    int l = l0 + tx * 4;
    float4 v = make_float4(acc[i][0], acc[i][1], acc[i][2], acc[i][3]);
    if (j < DI)
      *(float4*)&xi_t[((size_t)(b * DI + j)) * LSEQ + l] = v;
    else
      *(float4*)&z_t[((size_t)(b * DI + (j - DI))) * LSEQ + l] = v;
  }
}

// ---------------- conv + silu -> u_t ----------------
__global__ __launch_bounds__(256) void conv_silu(
    const float* __restrict__ xi_t, const float* __restrict__ cw,
    const float* __restrict__ cb, float* __restrict__ u_t) {
  int idx = blockIdx.x * 256 + threadIdx.x;
  int l = idx & (LSEQ - 1);
  int d = (idx >> 11) & (DI - 1);
  int b = idx >> 20;
  const float* xp = xi_t + ((size_t)(b * DI + d)) * LSEQ;
  float acc = cb[d];
#pragma unroll
  for (int k = 0; k < 4; ++k) {
    int ll = l - 3 + k;
    if (ll >= 0) acc = fmaf(xp[ll], cw[d * 4 + k], acc);
  }
  u_t[idx] = silu_f(acc);
}

// ---------------- GEMM2: x_proj ----------------
// per b: O[l(2048), j(136)] = sum_d u_t[b][d][l] * Wx[j][d]
__global__ __launch_bounds__(256) void gemm_xproj(
    const float* __restrict__ u_t, const float* __restrict__ Wx,
    float* __restrict__ dtr, float* __restrict__ Bb, float* __restrict__ Cb) {
  __shared__ float As[16][68];  // [d][l]
  __shared__ float Bs[16][68];  // [d][j]
  int tid = threadIdx.x;
  int tx = tid & 15, ty = tid >> 4;
  int l0 = blockIdx.x * 64, j0 = blockIdx.y * 64, b = blockIdx.z;
  const float* ub = u_t + (size_t)b * DI * LSEQ;
  float acc[4][4] = {};
  for (int k0 = 0; k0 < DI; k0 += 16) {
    {
      int ll = tid & 63, kk = tid >> 6;
#pragma unroll
      for (int i = 0; i < 4; ++i)
        As[kk + 4 * i][ll] = ub[(size_t)(k0 + kk + 4 * i) * LSEQ + l0 + ll];
    }
    {
      int kk = tid & 15, jj = tid >> 4;
#pragma unroll
      for (int i = 0; i < 4; ++i) {
        int j = j0 + jj + 16 * i;
        Bs[kk][jj + 16 * i] = (j < 136) ? Wx[(size_t)j * DI + k0 + kk] : 0.f;
      }
    }
    __syncthreads();
#pragma unroll
    for (int k = 0; k < 16; ++k) {
      float4 a = *(const float4*)&As[k][ty * 4];   // l dir
      float4 bv = *(const float4*)&Bs[k][tx * 4];  // j dir
      float av[4] = {a.x, a.y, a.z, a.w};
      float bw[4] = {bv.x, bv.y, bv.z, bv.w};
#pragma unroll
      for (int i = 0; i < 4; ++i)
#pragma unroll
        for (int j = 0; j < 4; ++j) acc[i][j] = fmaf(av[i], bw[j], acc[i][j]);
    }
    __syncthreads();
  }
#pragma unroll
  for (int i = 0; i < 4; ++i) {
    int l = l0 + ty * 4 + i;
    size_t bl = (size_t)b * LSEQ + l;
#pragma unroll
    for (int q = 0; q < 4; ++q) {
      int j = j0 + tx * 4 + q;
      float v = acc[i][q];
      if (j < DTRANK)
        dtr[bl * DTRANK + j] = v;
      else if (j < DTRANK + DS)
        Bb[bl * DS + (j - DTRANK)] = v;
      else if (j < DTRANK + 2 * DS)
        Cb[bl * DS + (j - DTRANK - DS)] = v;
    }
  }
}

// ---------------- dt GEMM (K=8) + softplus; also dtu ----------------
__global__ __launch_bounds__(256) void dt_kernel(
    const float* __restrict__ dtr, const float* __restrict__ Wd,
    const float* __restrict__ db, const float* __restrict__ u_t,
    float* __restrict__ dt_t, float* __restrict__ dtu_t) {
  int l = blockIdx.x * 256 + threadIdx.x;
  int d = blockIdx.y;
  int b = blockIdx.z;
  size_t bl = (size_t)b * LSEQ + l;
  float acc = db[d];
#pragma unroll
  for (int r = 0; r < DTRANK; ++r)
    acc = fmaf(dtr[bl * DTRANK + r], Wd[d * DTRANK + r], acc);
  float dtv = (acc > 20.f) ? acc : log1pf(__expf(acc));
  size_t o = ((size_t)(b * DI + d)) * LSEQ + l;
  dt_t[o] = dtv;
  dtu_t[o] = dtv * u_t[o];
}

// ---------------- scan: one wave per (b,d), lane = state index n ----------------
__global__ __launch_bounds__(64) void scan_kernel(
    const float* __restrict__ dt_t, const float* __restrict__ dtu_t,
    const float* __restrict__ Bb, const float* __restrict__ Cb,
    const float* __restrict__ A_log, float* __restrict__ y_t) {
  int d = blockIdx.x;
  int b = blockIdx.y;
  int lane = threadIdx.x;
  float An = -__expf(A_log[d * DS + lane]);
  const float* dtp = dt_t + ((size_t)(b * DI + d)) * LSEQ;
  const float* dtup = dtu_t + ((size_t)(b * DI + d)) * LSEQ;
  const float* Bp = Bb + (size_t)b * LSEQ * DS;
  const float* Cp = Cb + (size_t)b * LSEQ * DS;
  float* yp = y_t + ((size_t)(b * DI + d)) * LSEQ;
  float h = 0.f;
  for (int t0 = 0; t0 < LSEQ; t0 += 64) {
    float ybuf = 0.f;
    for (int tt = 0; tt < 64; ++tt) {
      int t = t0 + tt;
      float dtv = dtp[t];
      float dtuv = dtup[t];
      float Bn = Bp[(size_t)t * DS + lane];
      float Cn = Cp[(size_t)t * DS + lane];
      float dA = __expf(dtv * An);
      h = fmaf(dA, h, dtuv * Bn);
      float p = h * Cn;
#pragma unroll
      for (int off = 32; off; off >>= 1) p += __shfl_xor(p, off);
      if (tt == lane) ybuf = p;
    }
    yp[t0 + lane] = ybuf;
  }
}

// ---------------- combine: y2 = (y + u*D) * silu(z) ----------------
__global__ __launch_bounds__(256) void combine_kernel(
    const float* __restrict__ y_t, const float* __restrict__ u_t,
    const float* __restrict__ z_t, const float* __restrict__ Dv,
    float* __restrict__ y2_t) {
  int idx = blockIdx.x * 256 + threadIdx.x;
  int d = (idx >> 11) & (DI - 1);
  float y2 = fmaf(u_t[idx], Dv[d], y_t[idx]) * silu_f(z_t[idx]);
  y2_t[idx] = y2;
}

// ---------------- GEMM3: out_proj + residual ----------------
// per b: out[c][l] = x[b][c][l] + sum_d Wo[c][d] * y2_t[b][d][l]
__global__ __launch_bounds__(256) void gemm_outproj(
    const float* __restrict__ y2_t, const float* __restrict__ Wo,
    const float* __restrict__ x, float* __restrict__ out) {
  __shared__ float As[16][68];  // [d][c]
  __shared__ float Bs[16][68];  // [d][l]
  int tid = threadIdx.x;
  int tx = tid & 15, ty = tid >> 4;
  int l0 = blockIdx.x * 64, c0 = blockIdx.y * 64, b = blockIdx.z;
  const float* yb = y2_t + (size_t)b * DI * LSEQ;
  float acc[4][4] = {};
  for (int k0 = 0; k0 < DI; k0 += 16) {
    {
      int kk = tid & 15, cc = tid >> 4;
#pragma unroll
      for (int i = 0; i < 4; ++i)
        As[kk][cc + 16 * i] = Wo[(size_t)(c0 + cc + 16 * i) * DI + k0 + kk];
    }
    {
      int ll = tid & 63, kk = tid >> 6;
#pragma unroll
      for (int i = 0; i < 4; ++i)
        Bs[kk + 4 * i][ll] = yb[(size_t)(k0 + kk + 4 * i) * LSEQ + l0 + ll];
    }
    __syncthreads();
#pragma unroll
    for (int k = 0; k < 16; ++k) {
      float4 a = *(const float4*)&As[k][ty * 4];   // c dir
      float4 bv = *(const float4*)&Bs[k][tx * 4];  // l dir
      float av[4] = {a.x, a.y, a.z, a.w};
      float bw[4] = {bv.x, bv.y, bv.z, bv.w};
#pragma unroll
      for (int i = 0; i < 4; ++i)
#pragma unroll
        for (int j = 0; j < 4; ++j) acc[i][j] = fmaf(av[i], bw[j], acc[i][j]);
    }
    __syncthreads();
  }
#pragma unroll
  for (int i = 0; i < 4; ++i) {
    int c = c0 + ty * 4 + i;
    int l = l0 + tx * 4;
    size_t o = ((size_t)(b * CIN + c)) * LSEQ + l;
    float4 xv = *(const float4*)&x[o];
    float4 v = make_float4(acc[i][0] + xv.x, acc[i][1] + xv.y,
                           acc[i][2] + xv.z, acc[i][3] + xv.w);
    *(float4*)&out[o] = v;
  }
}

extern "C" void kernel_launch(void* const* d_in, const int* in_sizes, int n_in,
                              void* d_out, int out_size, void* d_ws, size_t ws_size,
                              hipStream_t stream) {
  (void)in_sizes; (void)n_in; (void)out_size; (void)ws_size;
  const float* x = (const float*)d_in[0];
  const float* Wi = (const float*)d_in[1];
  const float* cw = (const float*)d_in[2];
  const float* cb = (const float*)d_in[3];
  const float* Wx = (const float*)d_in[4];
  const float* Wd = (const float*)d_in[5];
  const float* db = (const float*)d_in[6];
  const float* A_log = (const float*)d_in[7];
  const float* Dv = (const float*)d_in[8];
  const float* Wo = (const float*)d_in[9];
  float* out = (float*)d_out;

  float* ws = (float*)d_ws;
  size_t S = (size_t)NB * DI * LSEQ;  // 4,194,304 floats
  float* P_y = ws;              // xi_t, later y_t
  float* P_z = ws + S;
  float* P_u = ws + 2 * S;
  float* P_dt = ws + 3 * S;     // dt_t, later y2_t
  float* P_dtu = ws + 4 * S;
  float* P_dtr = ws + 5 * S;                     // NB*LSEQ*8
  float* P_B = P_dtr + (size_t)NB * LSEQ * DTRANK;  // NB*LSEQ*64
  float* P_C = P_B + (size_t)NB * LSEQ * DS;

  // 1. in_proj
  gemm_inproj<<<dim3(LSEQ / 64, 1024 / 64, NB), 256, 0, stream>>>(x, Wi, P_y, P_z);
  // 2. conv + silu
  conv_silu<<<(NB * DI * LSEQ) / 256, 256, 0, stream>>>(P_y, cw, cb, P_u);
  // 3. x_proj
  gemm_xproj<<<dim3(LSEQ / 64, 3, NB), 256, 0, stream>>>(P_u, Wx, P_dtr, P_B, P_C);
  // 4. dt + softplus + dtu
  dt_kernel<<<dim3(LSEQ / 256, DI, NB), 256, 0, stream>>>(P_dtr, Wd, db, P_u, P_dt, P_dtu);
  // 5. selective scan (writes y into P_y, xi is dead)
  scan_kernel<<<dim3(DI, NB), 64, 0, stream>>>(P_dt, P_dtu, P_B, P_C, A_log, P_y);
  // 6. combine (writes y2 into P_dt, dt is dead)
  combine_kernel<<<(NB * DI * LSEQ) / 256, 256, 0, stream>>>(P_y, P_u, P_z, Dv, P_dt);
  // 7. out_proj + residual
  gemm_outproj<<<dim3(LSEQ / 64, CIN / 64, NB), 256, 0, stream>>>(P_dt, Wo, x, out);
}

// Round 2
// 301.347 us; speedup vs baseline: 2.5129x; 2.5129x over previous
//
#include <hip/hip_runtime.h>
#include <math.h>

#define LSEQ 2048
#define DI 512
#define DS 64
#define DTRANK 8
#define CIN 128
#define NB 4

__device__ __forceinline__ float silu_f(float v) { return v / (1.f + __expf(-v)); }

// ---------------- GEMM1: in_proj ----------------
// per b: O[j(1024), l(2048)] = Wi[1024,128] @ x_b[128,2048]
// j<512 -> xi_t[b][j][l], j>=512 -> z_t[b][j-512][l]
__global__ __launch_bounds__(256) void gemm_inproj(
    const float* __restrict__ x, const float* __restrict__ Wi,
    float* __restrict__ xi_t, float* __restrict__ z_t) {
  __shared__ float As[16][68];  // [k][j]
  __shared__ float Bs[16][68];  // [k][l]
  int tid = threadIdx.x;
  int tx = tid & 15, ty = tid >> 4;
  int l0 = blockIdx.x * 64, j0 = blockIdx.y * 64, b = blockIdx.z;
  const float* xb = x + (size_t)b * CIN * LSEQ;
  float acc[4][4] = {};
  for (int k0 = 0; k0 < CIN; k0 += 16) {
    {
      int kk = tid & 15, jj = tid >> 4;
#pragma unroll
      for (int i = 0; i < 4; ++i)
        As[kk][jj + 16 * i] = Wi[(size_t)(j0 + jj + 16 * i) * CIN + k0 + kk];
    }
    {
      int ll = tid & 63, kk = tid >> 6;
#pragma unroll
      for (int i = 0; i < 4; ++i)
        Bs[kk + 4 * i][ll] = xb[(size_t)(k0 + kk + 4 * i) * LSEQ + l0 + ll];
    }
    __syncthreads();
#pragma unroll
    for (int k = 0; k < 16; ++k) {
      float4 a = *(const float4*)&As[k][ty * 4];
      float4 bv = *(const float4*)&Bs[k][tx * 4];
      float av[4] = {a.x, a.y, a.z, a.w};
      float bw[4] = {bv.x, bv.y, bv.z, bv.w};
#pragma unroll
      for (int i = 0; i < 4; ++i)
#pragma unroll
        for (int j = 0; j < 4; ++j) acc[i][j] = fmaf(av[i], bw[j], acc[i][j]);
    }
    __syncthreads();
  }
#pragma unroll
  for (int i = 0; i < 4; ++i) {
    int j = j0 + ty * 4 + i;
    int l = l0 + tx * 4;
    float4 v = make_float4(acc[i][0], acc[i][1], acc[i][2], acc[i][3]);
    if (j < DI)
      *(float4*)&xi_t[((size_t)(b * DI + j)) * LSEQ + l] = v;
    else
      *(float4*)&z_t[((size_t)(b * DI + (j - DI))) * LSEQ + l] = v;
  }
}

// ---------------- conv + silu -> u_t ----------------
__global__ __launch_bounds__(256) void conv_silu(
    const float* __restrict__ xi_t, const float* __restrict__ cw,
    const float* __restrict__ cb, float* __restrict__ u_t) {
  int idx = blockIdx.x * 256 + threadIdx.x;
  int l = idx & (LSEQ - 1);
  int d = (idx >> 11) & (DI - 1);
  int b = idx >> 20;
  const float* xp = xi_t + ((size_t)(b * DI + d)) * LSEQ;
  float acc = cb[d];
#pragma unroll
  for (int k = 0; k < 4; ++k) {
    int ll = l - 3 + k;
    if (ll >= 0) acc = fmaf(xp[ll], cw[d * 4 + k], acc);
  }
  u_t[idx] = silu_f(acc);
}

// ---------------- GEMM2: x_proj ----------------
// per b: O[l(2048), j(136)] = sum_d u_t[b][d][l] * Wx[j][d]
__global__ __launch_bounds__(256) void gemm_xproj(
    const float* __restrict__ u_t, const float* __restrict__ Wx,
    float* __restrict__ dtr, float* __restrict__ Bb, float* __restrict__ Cb) {
  __shared__ float As[16][68];  // [d][l]
  __shared__ float Bs[16][68];  // [d][j]
  int tid = threadIdx.x;
  int tx = tid & 15, ty = tid >> 4;
  int l0 = blockIdx.x * 64, j0 = blockIdx.y * 64, b = blockIdx.z;
  const float* ub = u_t + (size_t)b * DI * LSEQ;
  float acc[4][4] = {};
  for (int k0 = 0; k0 < DI; k0 += 16) {
    {
      int ll = tid & 63, kk = tid >> 6;
#pragma unroll
      for (int i = 0; i < 4; ++i)
        As[kk + 4 * i][ll] = ub[(size_t)(k0 + kk + 4 * i) * LSEQ + l0 + ll];
    }
    {
      int kk = tid & 15, jj = tid >> 4;
#pragma unroll
      for (int i = 0; i < 4; ++i) {
        int j = j0 + jj + 16 * i;
        Bs[kk][jj + 16 * i] = (j < 136) ? Wx[(size_t)j * DI + k0 + kk] : 0.f;
      }
    }
    __syncthreads();
#pragma unroll
    for (int k = 0; k < 16; ++k) {
      float4 a = *(const float4*)&As[k][ty * 4];   // l dir
      float4 bv = *(const float4*)&Bs[k][tx * 4];  // j dir
      float av[4] = {a.x, a.y, a.z, a.w};
      float bw[4] = {bv.x, bv.y, bv.z, bv.w};
#pragma unroll
      for (int i = 0; i < 4; ++i)
#pragma unroll
        for (int j = 0; j < 4; ++j) acc[i][j] = fmaf(av[i], bw[j], acc[i][j]);
    }
    __syncthreads();
  }
#pragma unroll
  for (int i = 0; i < 4; ++i) {
    int l = l0 + ty * 4 + i;
    size_t bl = (size_t)b * LSEQ + l;
#pragma unroll
    for (int q = 0; q < 4; ++q) {
      int j = j0 + tx * 4 + q;
      float v = acc[i][q];
      if (j < DTRANK)
        dtr[bl * DTRANK + j] = v;
      else if (j < DTRANK + DS)
        Bb[bl * DS + (j - DTRANK)] = v;
      else if (j < DTRANK + 2 * DS)
        Cb[bl * DS + (j - DTRANK - DS)] = v;
    }
  }
}

// ---------------- dt GEMM (K=8) + softplus; also dtu ----------------
__global__ __launch_bounds__(256) void dt_kernel(
    const float* __restrict__ dtr, const float* __restrict__ Wd,
    const float* __restrict__ db, const float* __restrict__ u_t,
    float* __restrict__ dt_t, float* __restrict__ dtu_t) {
  int l = blockIdx.x * 256 + threadIdx.x;
  int d = blockIdx.y;
  int b = blockIdx.z;
  size_t bl = (size_t)b * LSEQ + l;
  float acc = db[d];
#pragma unroll
  for (int r = 0; r < DTRANK; ++r)
    acc = fmaf(dtr[bl * DTRANK + r], Wd[d * DTRANK + r], acc);
  float dtv = (acc > 20.f) ? acc : log1pf(__expf(acc));
  size_t o = ((size_t)(b * DI + d)) * LSEQ + l;
  dt_t[o] = dtv;
  dtu_t[o] = dtv * u_t[o];
}

// ---------------- scan: one wave per (b,d), lane = state index n ----------------
// Per 64-step block: lane n runs the h-recurrence for its state, writes
// p = h*C into sp[t][n] (stride 65 -> 2-way bank alias = free); then each
// lane reduces one timestep (row) over n. No cross-lane shuffles; B/C loads
// batched 32-deep into registers for memory-level parallelism.
__global__ __launch_bounds__(64) void scan_kernel(
    const float* __restrict__ dt_t, const float* __restrict__ dtu_t,
    const float* __restrict__ Bb, const float* __restrict__ Cb,
    const float* __restrict__ A_log, float* __restrict__ y_t) {
  __shared__ float sdt[64];
  __shared__ float sdtu[64];
  __shared__ float sp[64][65];
  int d = blockIdx.x;
  int b = blockIdx.y;
  int lane = threadIdx.x;
  float An = -__expf(A_log[d * DS + lane]);
  const float* dtp = dt_t + ((size_t)(b * DI + d)) * LSEQ;
  const float* dtup = dtu_t + ((size_t)(b * DI + d)) * LSEQ;
  const float* Bp = Bb + (size_t)b * LSEQ * DS;
  const float* Cp = Cb + (size_t)b * LSEQ * DS;
  float* yp = y_t + ((size_t)(b * DI + d)) * LSEQ;
  float h = 0.f;
  for (int t0 = 0; t0 < LSEQ; t0 += 64) {
    // stage dt/dtu for this 64-block (coalesced), share via LDS broadcast
    sdt[lane] = dtp[t0 + lane];
    sdtu[lane] = dtup[t0 + lane];
    __syncthreads();
#pragma unroll
    for (int sub = 0; sub < 2; ++sub) {
      float bv[32], cv[32];
#pragma unroll
      for (int i = 0; i < 32; ++i) {
        int t = t0 + sub * 32 + i;
        bv[i] = Bp[(size_t)t * DS + lane];
        cv[i] = Cp[(size_t)t * DS + lane];
      }
#pragma unroll
      for (int i = 0; i < 32; ++i) {
        int tt = sub * 32 + i;
        float dA = __expf(sdt[tt] * An);
        h = fmaf(dA, h, sdtu[tt] * bv[i]);
        sp[tt][lane] = h * cv[i];
      }
    }
    __syncthreads();
    // reduce: lane handles timestep t0+lane, sums its row over n
    float acc = 0.f;
#pragma unroll
    for (int k = 0; k < 64; ++k) acc += sp[lane][k];
    yp[t0 + lane] = acc;
    __syncthreads();
  }
}

// ---------------- combine: y2 = (y + u*D) * silu(z) ----------------
__global__ __launch_bounds__(256) void combine_kernel(
    const float* __restrict__ y_t, const float* __restrict__ u_t,
    const float* __restrict__ z_t, const float* __restrict__ Dv,
    float* __restrict__ y2_t) {
  int idx = blockIdx.x * 256 + threadIdx.x;
  int d = (idx >> 11) & (DI - 1);
  float y2 = fmaf(u_t[idx], Dv[d], y_t[idx]) * silu_f(z_t[idx]);
  y2_t[idx] = y2;
}

// ---------------- GEMM3: out_proj + residual ----------------
// per b: out[c][l] = x[b][c][l] + sum_d Wo[c][d] * y2_t[b][d][l]
__global__ __launch_bounds__(256) void gemm_outproj(
    const float* __restrict__ y2_t, const float* __restrict__ Wo,
    const float* __restrict__ x, float* __restrict__ out) {
  __shared__ float As[16][68];  // [d][c]
  __shared__ float Bs[16][68];  // [d][l]
  int tid = threadIdx.x;
  int tx = tid & 15, ty = tid >> 4;
  int l0 = blockIdx.x * 64, c0 = blockIdx.y * 64, b = blockIdx.z;
  const float* yb = y2_t + (size_t)b * DI * LSEQ;
  float acc[4][4] = {};
  for (int k0 = 0; k0 < DI; k0 += 16) {
    {
      int kk = tid & 15, cc = tid >> 4;
#pragma unroll
      for (int i = 0; i < 4; ++i)
        As[kk][cc + 16 * i] = Wo[(size_t)(c0 + cc + 16 * i) * DI + k0 + kk];
    }
    {
      int ll = tid & 63, kk = tid >> 6;
#pragma unroll
      for (int i = 0; i < 4; ++i)
        Bs[kk + 4 * i][ll] = yb[(size_t)(k0 + kk + 4 * i) * LSEQ + l0 + ll];
    }
    __syncthreads();
#pragma unroll
    for (int k = 0; k < 16; ++k) {
      float4 a = *(const float4*)&As[k][ty * 4];   // c dir
      float4 bv = *(const float4*)&Bs[k][tx * 4];  // l dir
      float av[4] = {a.x, a.y, a.z, a.w};
      float bw[4] = {bv.x, bv.y, bv.z, bv.w};
#pragma unroll
      for (int i = 0; i < 4; ++i)
#pragma unroll
        for (int j = 0; j < 4; ++j) acc[i][j] = fmaf(av[i], bw[j], acc[i][j]);
    }
    __syncthreads();
  }
#pragma unroll
  for (int i = 0; i < 4; ++i) {
    int c = c0 + ty * 4 + i;
    int l = l0 + tx * 4;
    size_t o = ((size_t)(b * CIN + c)) * LSEQ + l;
    float4 xv = *(const float4*)&x[o];
    float4 v = make_float4(acc[i][0] + xv.x, acc[i][1] + xv.y,
                           acc[i][2] + xv.z, acc[i][3] + xv.w);
    *(float4*)&out[o] = v;
  }
}

extern "C" void kernel_launch(void* const* d_in, const int* in_sizes, int n_in,
                              void* d_out, int out_size, void* d_ws, size_t ws_size,
                              hipStream_t stream) {
  (void)in_sizes; (void)n_in; (void)out_size; (void)ws_size;
  const float* x = (const float*)d_in[0];
  const float* Wi = (const float*)d_in[1];
  const float* cw = (const float*)d_in[2];
  const float* cb = (const float*)d_in[3];
  const float* Wx = (const float*)d_in[4];
  const float* Wd = (const float*)d_in[5];
  const float* db = (const float*)d_in[6];
  const float* A_log = (const float*)d_in[7];
  const float* Dv = (const float*)d_in[8];
  const float* Wo = (const float*)d_in[9];
  float* out = (float*)d_out;

  float* ws = (float*)d_ws;
  size_t S = (size_t)NB * DI * LSEQ;  // 4,194,304 floats
  float* P_y = ws;              // xi_t, later y_t
  float* P_z = ws + S;
  float* P_u = ws + 2 * S;
  float* P_dt = ws + 3 * S;     // dt_t, later y2_t
  float* P_dtu = ws + 4 * S;
  float* P_dtr = ws + 5 * S;                     // NB*LSEQ*8
  float* P_B = P_dtr + (size_t)NB * LSEQ * DTRANK;  // NB*LSEQ*64
  float* P_C = P_B + (size_t)NB * LSEQ * DS;

  // 1. in_proj
  gemm_inproj<<<dim3(LSEQ / 64, 1024 / 64, NB), 256, 0, stream>>>(x, Wi, P_y, P_z);
  // 2. conv + silu
  conv_silu<<<(NB * DI * LSEQ) / 256, 256, 0, stream>>>(P_y, cw, cb, P_u);
  // 3. x_proj
  gemm_xproj<<<dim3(LSEQ / 64, 3, NB), 256, 0, stream>>>(P_u, Wx, P_dtr, P_B, P_C);
  // 4. dt + softplus + dtu
  dt_kernel<<<dim3(LSEQ / 256, DI, NB), 256, 0, stream>>>(P_dtr, Wd, db, P_u, P_dt, P_dtu);
  // 5. selective scan (writes y into P_y, xi is dead)
  scan_kernel<<<dim3(DI, NB), 64, 0, stream>>>(P_dt, P_dtu, P_B, P_C, A_log, P_y);
  // 6. combine (writes y2 into P_dt, dt is dead)
  combine_kernel<<<(NB * DI * LSEQ) / 256, 256, 0, stream>>>(P_y, P_u, P_z, Dv, P_dt);
  // 7. out_proj + residual
  gemm_outproj<<<dim3(LSEQ / 64, CIN / 64, NB), 256, 0, stream>>>(P_dt, Wo, x, out);
}